// Round 4
// baseline (64.970 us; speedup 1.0000x reference)
//
#include <hip/hip_runtime.h>

// HardEMQuantizer forward:
//   logits:     (B=8, T=2048, M*K=4096) fp32  -> N = 16384 rows, M=8 splits, K=512 codes
//   embeddings: (M=8, K=512, D=64) fp32
// Outputs (concatenated flat, fp32):
//   [0 .. 8388608)         quantized        = gather of argmax embedding rows
//   [8388608 .. 16777216)  quantized_stack  = same flat data
//   [16777216 .. 16908288) encoding_indices = argmax index as float
//
// Forward value of straight-through z is exactly one_hot(argmax) -> row gather;
// argmax(softmax(x)) == argmax(x).
//
// R4: persistent pipelined waves. 8192 waves, each owns 16 consecutive tasks
// (8 iterations x 2 tasks). Next iteration's 4 KiB of logits is prefetched
// before the current iteration's reduce/gather/store, so every wave keeps
// loads in flight continuously (R2's burst structure had dead time).
// Fully unrolled -> all register indexing static (no scratch).

#define MM 8
#define KK 512
#define DD 64
#define ITERS 8

typedef float f32x4 __attribute__((ext_vector_type(4)));

__device__ inline void task_argmax(f32x4 a, f32x4 b, int lane, float& best, int& bidx) {
    int k0 = lane * 4;
    best = a.x; bidx = k0;
    if (a.y > best) { best = a.y; bidx = k0 + 1; }
    if (a.z > best) { best = a.z; bidx = k0 + 2; }
    if (a.w > best) { best = a.w; bidx = k0 + 3; }
    int k1 = 256 + lane * 4;
    if (b.x > best) { best = b.x; bidx = k1;     }
    if (b.y > best) { best = b.y; bidx = k1 + 1; }
    if (b.z > best) { best = b.z; bidx = k1 + 2; }
    if (b.w > best) { best = b.w; bidx = k1 + 3; }
}

__global__ __launch_bounds__(256) void hardem_fwd(
    const float* __restrict__ logits,   // (N*M, K) contiguous
    const float* __restrict__ emb,      // (M, K, D)
    float* __restrict__ out)
{
    const int wave = threadIdx.x >> 6;
    const int lane = threadIdx.x & 63;
    const int wid  = blockIdx.x * 4 + wave;       // 0..8191
    const int base = wid * (2 * ITERS);           // 16 consecutive tasks

    // Prefetch iteration 0 (two tasks, 4x 1 KiB coalesced NT loads).
    const f32x4* p0 = (const f32x4*)(logits + (size_t)(base + 0) * KK);
    const f32x4* p1 = (const f32x4*)(logits + (size_t)(base + 1) * KK);
    f32x4 A0 = __builtin_nontemporal_load(&p0[lane]);
    f32x4 B0 = __builtin_nontemporal_load(&p0[64 + lane]);
    f32x4 A1 = __builtin_nontemporal_load(&p1[lane]);
    f32x4 B1 = __builtin_nontemporal_load(&p1[64 + lane]);

    #pragma unroll
    for (int it = 0; it < ITERS; ++it) {
        const int t0 = base + it * 2;

        // Prefetch next iteration before touching current data.
        f32x4 nA0, nB0, nA1, nB1;
        if (it + 1 < ITERS) {
            const f32x4* q0 = (const f32x4*)(logits + (size_t)(t0 + 2) * KK);
            const f32x4* q1 = (const f32x4*)(logits + (size_t)(t0 + 3) * KK);
            nA0 = __builtin_nontemporal_load(&q0[lane]);
            nB0 = __builtin_nontemporal_load(&q0[64 + lane]);
            nA1 = __builtin_nontemporal_load(&q1[lane]);
            nB1 = __builtin_nontemporal_load(&q1[64 + lane]);
        }

        // In-lane argmax (first-index tie-break via strict >), then butterfly.
        float v0, v1; int i0, i1;
        task_argmax(A0, B0, lane, v0, i0);
        task_argmax(A1, B1, lane, v1, i1);

        #pragma unroll
        for (int mask = 1; mask < 64; mask <<= 1) {
            float o0 = __shfl_xor(v0, mask, 64);  int j0 = __shfl_xor(i0, mask, 64);
            float o1 = __shfl_xor(v1, mask, 64);  int j1 = __shfl_xor(i1, mask, 64);
            if (o0 > v0 || (o0 == v0 && j0 < i0)) { v0 = o0; i0 = j0; }
            if (o1 > v1 || (o1 == v1 && j1 < i1)) { v1 = o1; i1 = j1; }
        }

        // Embedding-row gathers (emb is 1 MiB -> cache-resident; NT loads
        // on logits keep it from being evicted).
        const int m0 = (t0 + 0) & (MM - 1);
        const int m1 = (t0 + 1) & (MM - 1);
        float e0 = emb[((size_t)m0 * KK + (size_t)i0) * DD + lane];
        float e1 = emb[((size_t)m1 * KK + (size_t)i1) * DD + lane];

        const size_t q0 = (size_t)t0 * DD + lane;
        __builtin_nontemporal_store(e0, &out[q0]);                 // quantized
        __builtin_nontemporal_store(e1, &out[q0 + DD]);
        __builtin_nontemporal_store(e0, &out[8388608 + q0]);       // quantized_stack
        __builtin_nontemporal_store(e1, &out[8388608 + q0 + DD]);

        if (lane < 2)                                              // indices
            out[16777216 + (size_t)t0 + lane] = (float)(lane ? i1 : i0);

        A0 = nA0; B0 = nB0; A1 = nA1; B1 = nB1;
    }
}

extern "C" void kernel_launch(void* const* d_in, const int* in_sizes, int n_in,
                              void* d_out, int out_size, void* d_ws, size_t ws_size,
                              hipStream_t stream) {
    const float* logits = (const float*)d_in[0];
    const float* emb    = (const float*)d_in[1];
    float* out          = (float*)d_out;

    // 131072 tasks / 16 per wave = 8192 waves = 2048 blocks of 4 waves.
    hardem_fwd<<<2048, 256, 0, stream>>>(logits, emb, out);
}

// Round 5
// 56.056 us; speedup vs baseline: 1.1590x; 1.1590x over previous
//
#include <hip/hip_runtime.h>

// HardEMQuantizer forward:
//   logits:     (B=8, T=2048, M*K=4096) fp32  -> N = 16384 rows, M=8 splits, K=512 codes
//   embeddings: (M=8, K=512, D=64) fp32
// Outputs (concatenated flat, fp32):
//   [0 .. 8388608)         quantized        = gather of argmax embedding rows
//   [8388608 .. 16777216)  quantized_stack  = same flat data
//   [16777216 .. 16908288) encoding_indices = argmax index as float
//
// R5: two-kernel split to attack read/write stream mixing.
//   K1: pure-read argmax (R2 structure, 2 tasks/wave, 65536 waves), writes only
//       the 0.5 MB float indices.
//   K2: pure-write scatter: 4 tasks/wave, each 16-lane group gathers one
//       embedding row as float4 (256 B contiguous, L2-resident) and NT-stores
//       it to both output copies (fully coalesced 1 KiB/wave/buffer).
// Kernel-boundary ordering makes K1's index writes visible to K2.

#define MM 8
#define KK 512
#define DD 64

typedef float f32x4 __attribute__((ext_vector_type(4)));

__device__ inline void task_argmax(f32x4 a, f32x4 b, int lane, float& best, int& bidx) {
    int k0 = lane * 4;
    best = a.x; bidx = k0;
    if (a.y > best) { best = a.y; bidx = k0 + 1; }
    if (a.z > best) { best = a.z; bidx = k0 + 2; }
    if (a.w > best) { best = a.w; bidx = k0 + 3; }
    int k1 = 256 + lane * 4;
    if (b.x > best) { best = b.x; bidx = k1;     }
    if (b.y > best) { best = b.y; bidx = k1 + 1; }
    if (b.z > best) { best = b.z; bidx = k1 + 2; }
    if (b.w > best) { best = b.w; bidx = k1 + 3; }
}

__global__ __launch_bounds__(256) void hardem_argmax(
    const float* __restrict__ logits,   // (N*M, K) contiguous
    float* __restrict__ out)
{
    const int wave = threadIdx.x >> 6;
    const int lane = threadIdx.x & 63;
    const int wid  = blockIdx.x * 4 + wave;
    const int t0   = wid * 2;

    const f32x4* s0 = (const f32x4*)(logits + (size_t)t0 * KK);
    const f32x4* s1 = (const f32x4*)(logits + (size_t)(t0 + 1) * KK);
    f32x4 a0 = __builtin_nontemporal_load(&s0[lane]);
    f32x4 b0 = __builtin_nontemporal_load(&s0[64 + lane]);
    f32x4 a1 = __builtin_nontemporal_load(&s1[lane]);
    f32x4 b1 = __builtin_nontemporal_load(&s1[64 + lane]);

    float v0, v1; int i0, i1;
    task_argmax(a0, b0, lane, v0, i0);
    task_argmax(a1, b1, lane, v1, i1);

    #pragma unroll
    for (int mask = 1; mask < 64; mask <<= 1) {
        float o0 = __shfl_xor(v0, mask, 64);  int j0 = __shfl_xor(i0, mask, 64);
        float o1 = __shfl_xor(v1, mask, 64);  int j1 = __shfl_xor(i1, mask, 64);
        if (o0 > v0 || (o0 == v0 && j0 < i0)) { v0 = o0; i0 = j0; }
        if (o1 > v1 || (o1 == v1 && j1 < i1)) { v1 = o1; i1 = j1; }
    }

    if (lane < 2)
        out[16777216 + (size_t)t0 + lane] = (float)(lane ? i1 : i0);
}

__global__ __launch_bounds__(256) void hardem_scatter(
    const float* __restrict__ emb,      // (M, K, D)
    float* __restrict__ out)
{
    const int wave = threadIdx.x >> 6;
    const int lane = threadIdx.x & 63;
    const int wid  = blockIdx.x * 4 + wave;   // 0..32767
    const int base = wid * 4;                 // 4 tasks per wave

    // lanes 0..3 read the 4 task indices (just written by K1, L2-hot)
    float idxf = 0.0f;
    if (lane < 4) idxf = out[16777216 + (size_t)base + lane];

    const int g = lane >> 4;                  // task group within wave, 0..3
    const int o = lane & 15;                  // float4 slot within the 64-float row
    const int idx = (int)__shfl(idxf, g, 64); // exact for 0..511
    const int t = base + g;
    const int m = t & (MM - 1);

    const f32x4* erow = (const f32x4*)(emb + ((size_t)m * KK + (size_t)idx) * DD);
    f32x4 e = erow[o];                        // 16 lanes x 16B = one 256B row

    f32x4* q  = (f32x4*)(out + (size_t)t * DD);
    f32x4* qs = (f32x4*)(out + 8388608 + (size_t)t * DD);
    __builtin_nontemporal_store(e, &q[o]);    // quantized
    __builtin_nontemporal_store(e, &qs[o]);   // quantized_stack
}

extern "C" void kernel_launch(void* const* d_in, const int* in_sizes, int n_in,
                              void* d_out, int out_size, void* d_ws, size_t ws_size,
                              hipStream_t stream) {
    const float* logits = (const float*)d_in[0];
    const float* emb    = (const float*)d_in[1];
    float* out          = (float*)d_out;

    // K1: 131072 tasks, 2 per wave, 4 waves/block -> 16384 blocks (pure read)
    hardem_argmax<<<16384, 256, 0, stream>>>(logits, out);
    // K2: 131072 tasks, 4 per wave, 4 waves/block -> 8192 blocks (pure write)
    hardem_scatter<<<8192, 256, 0, stream>>>(emb, out);
}